// Round 1
// baseline (1947.982 us; speedup 1.0000x reference)
//
#include <hip/hip_runtime.h>
#include <stdint.h>

// Problem constants (n=1, c=32, h=w=128, p=3)
#define NPT  16384          // number of points (h*w)
#define DK   288            // c*p*p
#define NCHK 128            // grid chunks per dim (16384/128)

#define TM 128
#define TN 128
#define BK 8

// ---------------- feature extraction (k-major: F[k*NPT + point]) -------------
__global__ void extract_kernel(const float* __restrict__ src,
                               const float* __restrict__ tgt,
                               float* __restrict__ Q, float* __restrict__ P) {
  int idx = blockIdx.x * 256 + threadIdx.x;
  if (idx >= DK * NPT) return;
  int k  = idx >> 14;          // / 16384
  int pt = idx & (NPT - 1);
  int y = pt >> 7, x = pt & 127;
  int c = k / 9;
  int r = k - c * 9;
  int dy = r / 3, dx = r - dy * 3;
  int yy = y + dy - 1; yy = yy < 0 ? 0 : (yy > 127 ? 127 : yy);
  int xx = x + dx - 1; xx = xx < 0 ? 0 : (xx > 127 ? 127 : xx);
  int m = (c << 14) + (yy << 7) + xx;
  Q[idx] = src[m];
  P[idx] = tgt[m];
}

// ------------- norms (fp64 accumulate) + init of packed argmin ---------------
__global__ void norms_kernel(const float* __restrict__ Q,
                             const float* __restrict__ P,
                             float* __restrict__ rq, float* __restrict__ rp,
                             unsigned long long* __restrict__ best) {
  int i = blockIdx.x * 256 + threadIdx.x;
  if (i >= NPT) return;
  double sq = 0.0, sp = 0.0;
  for (int k = 0; k < DK; ++k) {
    float a = Q[k * NPT + i]; sq += (double)a * (double)a;
    float b = P[k * NPT + i]; sp += (double)b * (double)b;
  }
  rq[i] = (float)sq;
  rp[i] = (float)sp;
  best[i] = 0xFFFFFFFFFFFFFFFFULL;
}

// ------------------- fused GEMM + row-argmin ---------------------------------
// rows a = query index (Q), cols b = target index (P).
// minimized quantity per row: f(b) = rq[b] - 2 * (q_a . p_b)
__global__ __launch_bounds__(256, 2)
void gemm_argmin_kernel(const float* __restrict__ Q,
                        const float* __restrict__ P,
                        const float* __restrict__ rq,
                        unsigned long long* __restrict__ best) {
  __shared__ float As[BK][TM];
  __shared__ float Bs[BK][TN];

  const int nBase = blockIdx.x * TN;
  const int mBase = blockIdx.y * TM;

  const int tid = threadIdx.x;
  const int tx = tid & 15;     // column group
  const int ty = tid >> 4;     // row group

  // staging: thread loads one float4 of row skk at offset soff
  const int skk  = tid >> 5;          // 0..7
  const int soff = (tid & 31) * 4;    // 0..124

  const float4* Qv = (const float4*)(Q + mBase + soff);
  const float4* Pv = (const float4*)(P + nBase + soff);
  const int rowStride4 = NPT / 4;

  float acc[8][8];
#pragma unroll
  for (int i = 0; i < 8; ++i)
#pragma unroll
    for (int j = 0; j < 8; ++j) acc[i][j] = 0.0f;

  // prefetch chunk 0
  float4 aReg = Qv[skk * rowStride4];
  float4 bReg = Pv[skk * rowStride4];

  for (int kc = 0; kc < DK / BK; ++kc) {
    __syncthreads();
    *(float4*)&As[skk][soff] = aReg;
    *(float4*)&Bs[skk][soff] = bReg;
    __syncthreads();
    if (kc + 1 < DK / BK) {
      int krow = (kc + 1) * BK + skk;
      aReg = Qv[krow * rowStride4];
      bReg = Pv[krow * rowStride4];
    }
#pragma unroll
    for (int kk = 0; kk < BK; ++kk) {
      float4 a0 = *(const float4*)&As[kk][ty * 4];
      float4 a1 = *(const float4*)&As[kk][64 + ty * 4];
      float4 b0 = *(const float4*)&Bs[kk][tx * 4];
      float4 b1 = *(const float4*)&Bs[kk][64 + tx * 4];
      float av[8] = {a0.x, a0.y, a0.z, a0.w, a1.x, a1.y, a1.z, a1.w};
      float bv[8] = {b0.x, b0.y, b0.z, b0.w, b1.x, b1.y, b1.z, b1.w};
#pragma unroll
      for (int i = 0; i < 8; ++i)
#pragma unroll
        for (int j = 0; j < 8; ++j)
          acc[i][j] = fmaf(av[i], bv[j], acc[i][j]);
    }
  }

  // epilogue
  int cols[8];
  float rqv[8];
#pragma unroll
  for (int j = 0; j < 8; ++j) {
    int c = (j < 4) ? (tx * 4 + j) : (64 + tx * 4 + (j - 4));
    cols[j] = nBase + c;
    rqv[j] = rq[cols[j]];
  }

#pragma unroll
  for (int i = 0; i < 8; ++i) {
    unsigned long long pk = 0xFFFFFFFFFFFFFFFFULL;
#pragma unroll
    for (int j = 0; j < 8; ++j) {
      float f = fmaf(-2.0f, acc[i][j], rqv[j]);
      unsigned int bits = __float_as_uint(f);
      unsigned int key = (bits & 0x80000000u) ? ~bits : (bits | 0x80000000u);
      unsigned long long cand =
          ((unsigned long long)key << 32) | (unsigned long long)(unsigned)cols[j];
      pk = pk < cand ? pk : cand;
    }
    // reduce across the 16 lanes (same ty) holding this row's columns
#pragma unroll
    for (int s = 1; s < 16; s <<= 1) {
      unsigned long long o = __shfl_xor(pk, s, 16);
      pk = pk < o ? pk : o;
    }
    if (tx == 0) {
      int row = mBase + ((i < 4) ? (ty * 4 + i) : (64 + ty * 4 + (i - 4)));
      atomicMin(best + row, pk);
    }
  }
}

// ---------------------------- finalize ---------------------------------------
// out layout (floats): [0, NPT)      = idy (nnf plane 0)
//                      [NPT, 2*NPT)  = idx (nnf plane 1)
//                      [2*NPT, 3*NPT)= nnd
__global__ void finalize_kernel(const unsigned long long* __restrict__ best,
                                const float* __restrict__ rp,
                                float* __restrict__ out) {
  int i = blockIdx.x * 256 + threadIdx.x;
  if (i >= NPT) return;
  unsigned long long v = best[i];
  unsigned int col = (unsigned int)(v & 0xFFFFFFFFu);
  unsigned int key = (unsigned int)(v >> 32);
  unsigned int bits = (key & 0x80000000u) ? (key & 0x7FFFFFFFu) : ~key;
  float fmin = __uint_as_float(bits);
  float dist = rp[i] + fmin;
  out[i]           = (float)(col >> 7);   // idy = b / 128
  out[NPT + i]     = (float)(col & 127);  // idx = b % 128
  out[2 * NPT + i] = dist;                // nnd
}

extern "C" void kernel_launch(void* const* d_in, const int* in_sizes, int n_in,
                              void* d_out, int out_size, void* d_ws, size_t ws_size,
                              hipStream_t stream) {
  const float* src = (const float*)d_in[0];  // source_map (1,32,128,128)
  const float* tgt = (const float*)d_in[1];  // target_map (1,32,128,128)
  float* out = (float*)d_out;                // 3*NPT floats (nnf int values as float, nnd)

  // workspace layout (bytes):
  //   Q   : [0, 18874368)            288*16384 fp32 (k-major)
  //   P   : [18874368, 37748736)
  //   rq  : [37748736, 37814272)     16384 fp32
  //   rp  : [37814272, 37879808)     16384 fp32
  //   best: [37879808, 38010880)     16384 u64 packed (key<<32)|col
  char* ws = (char*)d_ws;
  float* Q = (float*)(ws);
  float* P = (float*)(ws + 18874368);
  float* rq = (float*)(ws + 37748736);
  float* rp = (float*)(ws + 37814272);
  unsigned long long* best = (unsigned long long*)(ws + 37879808);

  // 1. patch feature extraction
  {
    int total = DK * NPT;
    int blocks = (total + 255) / 256;
    extract_kernel<<<blocks, 256, 0, stream>>>(src, tgt, Q, P);
  }
  // 2. norms + init
  norms_kernel<<<(NPT + 255) / 256, 256, 0, stream>>>(Q, P, rq, rp, best);
  // 3. fused GEMM + argmin
  {
    dim3 grid(NCHK, NCHK);
    gemm_argmin_kernel<<<grid, 256, 0, stream>>>(Q, P, rq, best);
  }
  // 4. finalize outputs
  finalize_kernel<<<(NPT + 255) / 256, 256, 0, stream>>>(best, rp, out);
}

// Round 2
// 872.306 us; speedup vs baseline: 2.2331x; 2.2331x over previous
//
#include <hip/hip_runtime.h>
#include <stdint.h>

// Problem constants (n=1, c=32, h=w=128, p=3)
#define NPT    16384        // points (h*w)
#define KD     288          // c*p*p
#define KE     576          // per-point row: [hi(288) | lo(288)] f16
#define NCHUNK 27           // 3 products x 9 chunks of K=32

typedef _Float16 f16;
typedef __attribute__((ext_vector_type(8))) _Float16 half8;
typedef __attribute__((ext_vector_type(4))) float floatx4;

#define AS1(p) ((const __attribute__((address_space(1))) uint32_t*)(p))
#define AS3(p) ((__attribute__((address_space(3))) uint32_t*)(p))

// ---------------- patch extraction + fp32->2xf16 split -----------------------
// Aext[point][0..287]=hi(src patch feat), [288..575]=lo. Bext same for tgt.
__global__ void extract_split_kernel(const float* __restrict__ src,
                                     const float* __restrict__ tgt,
                                     f16* __restrict__ Aext,
                                     f16* __restrict__ Bext) {
  int tid = blockIdx.x * 256 + threadIdx.x;   // 16384*32 threads
  int point = tid >> 5;
  int c = tid & 31;
  int y = point >> 7, x = point & 127;
  f16* arow = Aext + (size_t)point * KE;
  f16* brow = Bext + (size_t)point * KE;
#pragma unroll
  for (int dy = 0; dy < 3; ++dy) {
    int yy = y + dy - 1; yy = yy < 0 ? 0 : (yy > 127 ? 127 : yy);
#pragma unroll
    for (int dx = 0; dx < 3; ++dx) {
      int xx = x + dx - 1; xx = xx < 0 ? 0 : (xx > 127 ? 127 : xx);
      int k = c * 9 + dy * 3 + dx;
      int m = (c << 14) + (yy << 7) + xx;
      float v = src[m];
      f16 h = (f16)v;
      arow[k] = h; arow[KD + k] = (f16)(v - (float)h);
      v = tgt[m];
      h = (f16)v;
      brow[k] = h; brow[KD + k] = (f16)(v - (float)h);
    }
  }
}

// ------------- norms (fp64 accumulate from original fp32) + init -------------
__global__ void norms_kernel(const float* __restrict__ src,
                             const float* __restrict__ tgt,
                             float* __restrict__ rq, float* __restrict__ rp,
                             unsigned long long* __restrict__ best) {
  int i = blockIdx.x * 256 + threadIdx.x;
  if (i >= NPT) return;
  int y = i >> 7, x = i & 127;
  double sq = 0.0, sp = 0.0;
  for (int c = 0; c < 32; ++c) {
#pragma unroll
    for (int dy = 0; dy < 3; ++dy) {
      int yy = y + dy - 1; yy = yy < 0 ? 0 : (yy > 127 ? 127 : yy);
#pragma unroll
      for (int dx = 0; dx < 3; ++dx) {
        int xx = x + dx - 1; xx = xx < 0 ? 0 : (xx > 127 ? 127 : xx);
        int m = (c << 14) + (yy << 7) + xx;
        float a = src[m]; sq += (double)a * (double)a;
        float b = tgt[m]; sp += (double)b * (double)b;
      }
    }
  }
  rq[i] = (float)sq;
  rp[i] = (float)sp;
  best[i] = 0xFFFFFFFFFFFFFFFFULL;
}

// ------------------- MFMA GEMM (3-product split) + fused row-argmin ----------
// rows = query points (Aext from source), cols = target points (Bext).
// minimized per row: f(col) = rq[col] - 2 * (q_row . p_col)
__global__ __launch_bounds__(256)
void gemm_argmin_kernel(const f16* __restrict__ A, const f16* __restrict__ B,
                        const float* __restrict__ rq,
                        unsigned long long* __restrict__ best) {
  // LDS tiles: 128 rows x 32 halves (64 B) each, physical slot order for
  // global_load_lds; logical slice s lives at phys slot t = s ^ ((row>>1)&3).
  __shared__ f16 Ash[128 * 32];
  __shared__ f16 Bsh[128 * 32];

  const int nBase = blockIdx.x * 128;
  const int mBase = blockIdx.y * 128;
  const int t = threadIdx.x;
  const int w = t >> 6;           // wave 0..3
  const int l = t & 63;

  // ---- staging decode (2 issues of 16B/lane per tile per wave) ----
  const int lr = l >> 2;          // row within 16-row issue group
  const int lt = l & 3;           // physical 16B slot within row
  const int s  = lt ^ ((lr >> 1) & 3);   // logical slice fetched (swizzle)
  const size_t aIdx0 = (size_t)(mBase + w * 32 + lr) * KE + s * 8;
  const size_t aIdx1 = aIdx0 + (size_t)16 * KE;
  const size_t bIdx0 = (size_t)(nBase + w * 32 + lr) * KE + s * 8;
  const size_t bIdx1 = bIdx0 + (size_t)16 * KE;

  // ---- fragment decode ----
  const int m16 = l & 15;
  const int q   = l >> 4;                 // k-quad
  const int tRd = q ^ ((m16 >> 1) & 3);   // swizzled phys slot for reads
  const int wRow = (w & 1) * 64;
  const int wCol = (w >> 1) * 64;

  floatx4 acc[4][4] = {};

  for (int kc = 0; kc < NCHUNK; ++kc) {
    int aOff, bOff;   // half offsets of this chunk's K-window
    if (kc < 9)       { aOff = kc * 32;              bOff = kc * 32; }        // hi.hi
    else if (kc < 18) { aOff = KD + (kc - 9) * 32;   bOff = (kc - 9) * 32; }  // lo.hi
    else              { aOff = (kc - 18) * 32;       bOff = KD + (kc - 18) * 32; } // hi.lo

    __syncthreads();   // previous iter's fragment reads complete
    __builtin_amdgcn_global_load_lds(AS1(A + aIdx0 + aOff), AS3(&Ash[w * 1024]),       16, 0, 0);
    __builtin_amdgcn_global_load_lds(AS1(A + aIdx1 + aOff), AS3(&Ash[w * 1024 + 512]), 16, 0, 0);
    __builtin_amdgcn_global_load_lds(AS1(B + bIdx0 + bOff), AS3(&Bsh[w * 1024]),       16, 0, 0);
    __builtin_amdgcn_global_load_lds(AS1(B + bIdx1 + bOff), AS3(&Bsh[w * 1024 + 512]), 16, 0, 0);
    __syncthreads();   // staging drained (vmcnt(0) before barrier)

    half8 af[4], bf[4];
#pragma unroll
    for (int i = 0; i < 4; ++i)
      af[i] = *(const half8*)&Ash[(wRow + i * 16 + m16) * 32 + tRd * 8];
#pragma unroll
    for (int j = 0; j < 4; ++j)
      bf[j] = *(const half8*)&Bsh[(wCol + j * 16 + m16) * 32 + tRd * 8];
#pragma unroll
    for (int i = 0; i < 4; ++i)
#pragma unroll
      for (int j = 0; j < 4; ++j)
        acc[i][j] = __builtin_amdgcn_mfma_f32_16x16x32_f16(af[i], bf[j], acc[i][j], 0, 0, 0);
  }

  // ---- epilogue: f = rq[col] - 2*dot, packed argmin ----
  // C/D layout (16x16): col = lane&15, row = (lane>>4)*4 + reg
  const int colBase = nBase + wCol + m16;
  float rqv[4];
#pragma unroll
  for (int j = 0; j < 4; ++j) rqv[j] = rq[colBase + j * 16];

#pragma unroll
  for (int i = 0; i < 4; ++i) {
    const int rowB = mBase + wRow + i * 16 + q * 4;
#pragma unroll
    for (int r = 0; r < 4; ++r) {
      unsigned long long pk = 0xFFFFFFFFFFFFFFFFULL;
#pragma unroll
      for (int j = 0; j < 4; ++j) {
        float f = fmaf(-2.0f, acc[i][j][r], rqv[j]);
        unsigned int bits = __float_as_uint(f);
        unsigned int key = (bits & 0x80000000u) ? ~bits : (bits | 0x80000000u);
        unsigned long long cand =
            ((unsigned long long)key << 32) | (unsigned)(colBase + j * 16);
        pk = pk < cand ? pk : cand;
      }
#pragma unroll
      for (int sft = 1; sft < 16; sft <<= 1) {
        unsigned long long o = __shfl_xor(pk, sft, 16);
        pk = pk < o ? pk : o;
      }
      if (m16 == 0) atomicMin(best + rowB + r, pk);
    }
  }
}

// ---------------------------- finalize ---------------------------------------
__global__ void finalize_kernel(const unsigned long long* __restrict__ best,
                                const float* __restrict__ rp,
                                float* __restrict__ out) {
  int i = blockIdx.x * 256 + threadIdx.x;
  if (i >= NPT) return;
  unsigned long long v = best[i];
  unsigned int col = (unsigned int)(v & 0xFFFFFFFFu);
  unsigned int key = (unsigned int)(v >> 32);
  unsigned int bits = (key & 0x80000000u) ? (key & 0x7FFFFFFFu) : ~key;
  float fmin = __uint_as_float(bits);
  out[i]           = (float)(col >> 7);   // idy
  out[NPT + i]     = (float)(col & 127);  // idx
  out[2 * NPT + i] = rp[i] + fmin;        // nnd
}

extern "C" void kernel_launch(void* const* d_in, const int* in_sizes, int n_in,
                              void* d_out, int out_size, void* d_ws, size_t ws_size,
                              hipStream_t stream) {
  const float* src = (const float*)d_in[0];  // source_map (1,32,128,128)
  const float* tgt = (const float*)d_in[1];  // target_map (1,32,128,128)
  float* out = (float*)d_out;

  // workspace layout (bytes):
  //   Aext: [0, 18874368)        16384 x 576 f16 (point-major [hi|lo])
  //   Bext: [18874368, 37748736)
  //   rq  : [37748736, 37814272) 16384 fp32 (query/source norms)
  //   rp  : [37814272, 37879808) 16384 fp32 (target norms)
  //   best: [37879808, 38010880) 16384 u64 packed (key<<32)|col
  char* ws = (char*)d_ws;
  f16* Aext = (f16*)(ws);
  f16* Bext = (f16*)(ws + 18874368);
  float* rq = (float*)(ws + 37748736);
  float* rp = (float*)(ws + 37814272);
  unsigned long long* best = (unsigned long long*)(ws + 37879808);

  extract_split_kernel<<<(NPT * 32) / 256, 256, 0, stream>>>(src, tgt, Aext, Bext);
  norms_kernel<<<NPT / 256, 256, 0, stream>>>(src, tgt, rq, rp, best);
  {
    dim3 grid(128, 128);
    gemm_argmin_kernel<<<grid, 256, 0, stream>>>(Aext, Bext, rq, best);
  }
  finalize_kernel<<<NPT / 256, 256, 0, stream>>>(best, rp, out);
}

// Round 3
// 804.028 us; speedup vs baseline: 2.4228x; 1.0849x over previous
//
#include <hip/hip_runtime.h>
#include <stdint.h>

// Problem constants (n=1, c=32, h=w=128, p=3)
#define NPT    16384        // points (h*w)
#define KD     288          // c*p*p
#define KE     576          // per-point row: [hi(288) | lo(288)] f16
#define NWIN   9            // 9 merged K-windows of 32 (hi+lo staged together)

typedef _Float16 f16;
typedef __attribute__((ext_vector_type(8))) _Float16 half8;
typedef __attribute__((ext_vector_type(4))) float floatx4;

#define AS1(p) ((const __attribute__((address_space(1))) uint32_t*)(p))
#define AS3(p) ((__attribute__((address_space(3))) uint32_t*)(p))

// ---------------- patch extraction + fp32->2xf16 split -----------------------
__global__ void extract_split_kernel(const float* __restrict__ src,
                                     const float* __restrict__ tgt,
                                     f16* __restrict__ Aext,
                                     f16* __restrict__ Bext) {
  int tid = blockIdx.x * 256 + threadIdx.x;   // 16384*32 threads
  int point = tid >> 5;
  int c = tid & 31;
  int y = point >> 7, x = point & 127;
  f16* arow = Aext + (size_t)point * KE;
  f16* brow = Bext + (size_t)point * KE;
#pragma unroll
  for (int dy = 0; dy < 3; ++dy) {
    int yy = y + dy - 1; yy = yy < 0 ? 0 : (yy > 127 ? 127 : yy);
#pragma unroll
    for (int dx = 0; dx < 3; ++dx) {
      int xx = x + dx - 1; xx = xx < 0 ? 0 : (xx > 127 ? 127 : xx);
      int k = c * 9 + dy * 3 + dx;
      int m = (c << 14) + (yy << 7) + xx;
      float v = src[m];
      f16 h = (f16)v;
      arow[k] = h; arow[KD + k] = (f16)(v - (float)h);
      v = tgt[m];
      h = (f16)v;
      brow[k] = h; brow[KD + k] = (f16)(v - (float)h);
    }
  }
}

// ------------- norms (fp64 accumulate from original fp32) + init -------------
__global__ void norms_kernel(const float* __restrict__ src,
                             const float* __restrict__ tgt,
                             float* __restrict__ rq, float* __restrict__ rp,
                             unsigned long long* __restrict__ best) {
  int i = blockIdx.x * 256 + threadIdx.x;
  if (i >= NPT) return;
  int y = i >> 7, x = i & 127;
  double sq = 0.0, sp = 0.0;
  for (int c = 0; c < 32; ++c) {
#pragma unroll
    for (int dy = 0; dy < 3; ++dy) {
      int yy = y + dy - 1; yy = yy < 0 ? 0 : (yy > 127 ? 127 : yy);
#pragma unroll
      for (int dx = 0; dx < 3; ++dx) {
        int xx = x + dx - 1; xx = xx < 0 ? 0 : (xx > 127 ? 127 : xx);
        int m = (c << 14) + (yy << 7) + xx;
        float a = src[m]; sq += (double)a * (double)a;
        float b = tgt[m]; sp += (double)b * (double)b;
      }
    }
  }
  rq[i] = (float)sq;
  rp[i] = (float)sp;
  best[i] = 0xFFFFFFFFFFFFFFFFULL;
}

// ------------- MFMA GEMM (merged split-products, dbuf pipeline) --------------
// Tile layout per buffer: 128 rows x 64 halves (8 slots of 8 halves = 16 B).
// Logical slice s of row r lives at phys slot (s ^ (r & 7)):
//   s in [0,4): hi window octet s;  s in [4,8): lo window octet s-4.
__global__ __launch_bounds__(256)
void gemm_argmin_kernel(const f16* __restrict__ A, const f16* __restrict__ B,
                        const float* __restrict__ rq,
                        unsigned long long* __restrict__ best) {
  __shared__ f16 Ash[2][128 * 64];   // 32 KB
  __shared__ f16 Bsh[2][128 * 64];   // 32 KB

  const int nBase = blockIdx.x * 128;
  const int mBase = blockIdx.y * 128;
  const int t = threadIdx.x;
  const int w = t >> 6;           // wave 0..3
  const int l = t & 63;

  // ---- staging decode: per issue, 64 lanes cover 8 rows x 8 phys slots ----
  const int lr = l >> 3;                 // row within 8-row issue group
  const int lt = l & 7;                  // phys 16B slot
  const int sl = lt ^ (lr & 7);          // logical slice this lane fetches
  const int sColOff = (sl < 4) ? sl * 8 : KD + (sl & 3) * 8;  // + kw*32/window
  size_t aOff[4], bOff[4];
#pragma unroll
  for (int ig = 0; ig < 4; ++ig) {
    int row = w * 32 + ig * 8 + lr;
    aOff[ig] = (size_t)(mBase + row) * KE + sColOff;
    bOff[ig] = (size_t)(nBase + row) * KE + sColOff;
  }

  // ---- fragment decode ----
  const int m16 = l & 15;
  const int q   = l >> 4;                // k-quad
  const int pHi = q ^ (m16 & 7);         // phys slot of hi octet q
  const int pLo = pHi ^ 4;               // phys slot of lo octet q
  const int wRow = (w & 1) * 64;
  const int wCol = (w >> 1) * 64;
  const int aHiOff = m16 * 64 + pHi * 8; // + (wRow + i*16)*64
  const int aLoOff = m16 * 64 + pLo * 8;

  floatx4 acc[4][4] = {};

  // stage window kw into buffer buf (8 issues of 1024 B per wave)
  auto stage = [&](int kw, int buf) {
    const int kAdd = kw * 32;
#pragma unroll
    for (int ig = 0; ig < 4; ++ig)
      __builtin_amdgcn_global_load_lds(AS1(A + aOff[ig] + kAdd),
                                       AS3(&Ash[buf][(w * 32 + ig * 8) * 64]), 16, 0, 0);
#pragma unroll
    for (int ig = 0; ig < 4; ++ig)
      __builtin_amdgcn_global_load_lds(AS1(B + bOff[ig] + kAdd),
                                       AS3(&Bsh[buf][(w * 32 + ig * 8) * 64]), 16, 0, 0);
  };

  stage(0, 0);
  for (int kw = 0; kw < NWIN; ++kw) {
    const int buf = kw & 1;
    __syncthreads();                     // drains stage(kw); frees buf^1
    if (kw + 1 < NWIN) stage(kw + 1, buf ^ 1);

    half8 ah[4], bh[4], al[4], bl[4];
#pragma unroll
    for (int i = 0; i < 4; ++i)
      ah[i] = *(const half8*)&Ash[buf][(wRow + i * 16) * 64 + aHiOff];
#pragma unroll
    for (int j = 0; j < 4; ++j)
      bh[j] = *(const half8*)&Bsh[buf][(wCol + j * 16) * 64 + aHiOff];
#pragma unroll
    for (int i = 0; i < 4; ++i)
#pragma unroll
      for (int j = 0; j < 4; ++j)
        acc[i][j] = __builtin_amdgcn_mfma_f32_16x16x32_f16(ah[i], bh[j], acc[i][j], 0, 0, 0);

#pragma unroll
    for (int i = 0; i < 4; ++i)
      al[i] = *(const half8*)&Ash[buf][(wRow + i * 16) * 64 + aLoOff];
#pragma unroll
    for (int i = 0; i < 4; ++i)
#pragma unroll
      for (int j = 0; j < 4; ++j)
        acc[i][j] = __builtin_amdgcn_mfma_f32_16x16x32_f16(al[i], bh[j], acc[i][j], 0, 0, 0);

#pragma unroll
    for (int j = 0; j < 4; ++j)
      bl[j] = *(const half8*)&Bsh[buf][(wCol + j * 16) * 64 + aLoOff];
#pragma unroll
    for (int i = 0; i < 4; ++i)
#pragma unroll
      for (int j = 0; j < 4; ++j)
        acc[i][j] = __builtin_amdgcn_mfma_f32_16x16x32_f16(ah[i], bl[j], acc[i][j], 0, 0, 0);
  }

  // ---- epilogue: f = rq[col] - 2*dot, packed argmin ----
  // C/D layout (16x16): col = lane&15, row = (lane>>4)*4 + reg
  const int colBase = nBase + wCol + m16;
  float rqv[4];
#pragma unroll
  for (int j = 0; j < 4; ++j) rqv[j] = rq[colBase + j * 16];

#pragma unroll
  for (int i = 0; i < 4; ++i) {
    const int rowB = mBase + wRow + i * 16 + q * 4;
#pragma unroll
    for (int r = 0; r < 4; ++r) {
      unsigned long long pk = 0xFFFFFFFFFFFFFFFFULL;
#pragma unroll
      for (int j = 0; j < 4; ++j) {
        float f = fmaf(-2.0f, acc[i][j][r], rqv[j]);
        unsigned int bits = __float_as_uint(f);
        unsigned int key = (bits & 0x80000000u) ? ~bits : (bits | 0x80000000u);
        unsigned long long cand =
            ((unsigned long long)key << 32) | (unsigned)(colBase + j * 16);
        pk = pk < cand ? pk : cand;
      }
#pragma unroll
      for (int sft = 1; sft < 16; sft <<= 1) {
        unsigned long long o = __shfl_xor(pk, sft, 16);
        pk = pk < o ? pk : o;
      }
      if (m16 == 0) atomicMin(best + rowB + r, pk);
    }
  }
}

// ---------------------------- finalize ---------------------------------------
__global__ void finalize_kernel(const unsigned long long* __restrict__ best,
                                const float* __restrict__ rp,
                                float* __restrict__ out) {
  int i = blockIdx.x * 256 + threadIdx.x;
  if (i >= NPT) return;
  unsigned long long v = best[i];
  unsigned int col = (unsigned int)(v & 0xFFFFFFFFu);
  unsigned int key = (unsigned int)(v >> 32);
  unsigned int bits = (key & 0x80000000u) ? (key & 0x7FFFFFFFu) : ~key;
  float fmin = __uint_as_float(bits);
  out[i]           = (float)(col >> 7);   // idy
  out[NPT + i]     = (float)(col & 127);  // idx
  out[2 * NPT + i] = rp[i] + fmin;        // nnd
}

extern "C" void kernel_launch(void* const* d_in, const int* in_sizes, int n_in,
                              void* d_out, int out_size, void* d_ws, size_t ws_size,
                              hipStream_t stream) {
  const float* src = (const float*)d_in[0];  // source_map (1,32,128,128)
  const float* tgt = (const float*)d_in[1];  // target_map (1,32,128,128)
  float* out = (float*)d_out;

  // workspace layout (bytes):
  //   Aext: [0, 18874368)        16384 x 576 f16 (point-major [hi|lo])
  //   Bext: [18874368, 37748736)
  //   rq  : [37748736, 37814272) 16384 fp32 (target-side norms for the f-term)
  //   rp  : [37814272, 37879808)
  //   best: [37879808, 38010880) 16384 u64 packed (key<<32)|col
  char* ws = (char*)d_ws;
  f16* Aext = (f16*)(ws);
  f16* Bext = (f16*)(ws + 18874368);
  float* rq = (float*)(ws + 37748736);
  float* rp = (float*)(ws + 37814272);
  unsigned long long* best = (unsigned long long*)(ws + 37879808);

  extract_split_kernel<<<(NPT * 32) / 256, 256, 0, stream>>>(src, tgt, Aext, Bext);
  norms_kernel<<<NPT / 256, 256, 0, stream>>>(src, tgt, rq, rp, best);
  {
    dim3 grid(128, 128);
    gemm_argmin_kernel<<<grid, 256, 0, stream>>>(Aext, Bext, rq, best);
  }
  finalize_kernel<<<NPT / 256, 256, 0, stream>>>(best, rp, out);
}